// Round 5
// baseline (131.093 us; speedup 1.0000x reference)
//
#include <hip/hip_runtime.h>

#define NG 512
#define PLANE 512

// ws layout (float index):
//   [16 .. 16+8*513)   : packed params, 8 floats per gaussian:
//                        {A, B, C, mx, my, wr, wg, wb} (entry 512 = prefetch pad)
//   [4352 .. 4864)     : per-gaussian max slots t[n] = max log2(prob_n)
#define PRM_OFF  16
#define SLOT_OFF 4352

// One wave per gaussian (512 blocks x 64 threads): compute params redundantly
// in all lanes (HW trig/rcp), lane 0 publishes packed params; lanes scan the
// 512 rows (8 rows/lane) for the exact discrete max of t = log2(prob)
// (concave parabola in x per row -> vertex +/- lattice candidates),
// shfl-reduce, lane 0 stores the per-gaussian slot.
__global__ __launch_bounds__(64) void prep_kernel(
    const float* __restrict__ mean, const float* __restrict__ alpha,
    const float* __restrict__ scale, const float* __restrict__ theta,
    const float* __restrict__ rgb, const float* __restrict__ pixels,
    float* __restrict__ ws) {
    const int n    = blockIdx.x;        // 0..511
    const int lane = threadIdx.x;       // 0..63

    const float TWO_PI = 6.283185307179586f;
    float th = theta[n];
    float c = __builtin_amdgcn_cosf(th);   // cos(2*pi*th): v_cos takes revolutions
    float s = __builtin_amdgcn_sinf(th);
    float sx = scale[2 * n], sy = scale[2 * n + 1];

    // cov = rot @ smat @ smat^T @ rot^T (reference f32 order)
    float m200 = (c * sx) * sx;
    float m201 = (-(s * sy)) * sy;
    float m210 = (s * sx) * sx;
    float m211 = (c * sy) * sy;
    float a   = m200 * c + m201 * (-s);
    float b01 = m200 * s + m201 * c;
    float b10 = m210 * c + m211 * (-s);
    float d   = m210 * s + m211 * c;

    float det = a * d - b01 * b10;
    float rdet = __builtin_amdgcn_rcpf(det);
    float inv00 = d * rdet;
    float inv01 = -b01 * rdet;
    float inv10 = -b10 * rdet;
    float inv11 = a * rdet;

    float norm = __builtin_amdgcn_rcpf(TWO_PI * __builtin_amdgcn_sqrtf(det));
    const float K = -0.5f * 1.4426950408889634f;  // -0.5 * log2(e)

    float A_ = K * inv00;
    float B_ = K * (inv01 + inv10);
    float C_ = K * inv11;
    float mx = mean[2 * n], my = mean[2 * n + 1];
    // Lg = log2(norm) = -log2(2*pi) - 0.5*log2(det)
    float Lg = fmaf(-0.5f, __builtin_amdgcn_logf(det), -2.651496129472319f);

    if (lane == 0) {
        float w = alpha[n] * norm;
        float4* p = (float4*)(ws + PRM_OFF + 8 * n);
        p[0] = make_float4(A_, B_, C_, mx);
        p[1] = make_float4(my, w * rgb[3 * n], w * rgb[3 * n + 1], w * rgb[3 * n + 2]);
    }

    // row scan: 8 rows per lane
    float inv2A = __builtin_amdgcn_rcpf(2.0f * A_);
    float t = -1e30f;
#pragma unroll
    for (int k = 0; k < 8; ++k) {
        int r = lane + (k << 6);
        float y  = pixels[(r << 10) + 1];
        float dy = y - my;
        float bdy  = B_ * dy;
        float cdy2 = C_ * (dy * dy);
        float xstar = mx - bdy * inv2A;
        float xs = fminf(fmaxf(xstar, 0.0f), 1.0f);   // NaN-safe clamp
        int i1 = min((int)(xs * 511.0f), 510);
#pragma unroll
        for (int kk = -1; kk <= 2; ++kk) {
            int i = max(0, min(i1 + kk, 511));
            float x = pixels[(r << 10) + (i << 1)];
            float dx = x - mx;
            float q = fmaf(fmaf(A_, dx, bdy), dx, cdy2);
            t = fmaxf(t, q);
        }
    }
    t += Lg;
#pragma unroll
    for (int off = 32; off > 0; off >>= 1)
        t = fmaxf(t, __shfl_xor(t, off));
    if (lane == 0) ws[SLOT_OFF + n] = t;
}

// 2048 blocks x 256 threads (8 blocks/CU -> 32 waves/CU).
// Block covers 64 pixel-pairs; wave wv processes gaussians [wv*128,(wv+1)*128)
// (param addresses wave-uniform -> scalar loads). Partial sums combine in LDS;
// wave 0 applies max-normalization + sigmoid and stores.
__global__ __launch_bounds__(256, 8) void splat_kernel(
    const float* __restrict__ pixels, const float* __restrict__ ws,
    float* __restrict__ out) {
    const int tid  = threadIdx.x;
    const int wv   = tid >> 6;        // gaussian chunk 0..3
    const int lane = tid & 63;
    const int pair = blockIdx.x * 64 + lane;     // 0..131071
    const int row  = pair >> 8;
    const int col0 = (pair & 255) << 1;
    const int pbase = row * PLANE + col0;

    // one dwordx4: {x0, y, x1, y}
    float4 pix = *reinterpret_cast<const float4*>(pixels + 2 * pbase);
    const float x0 = pix.x, y = pix.y, x1 = pix.z;

    const float4* prm4 = reinterpret_cast<const float4*>(ws + PRM_OFF) + (wv << 8);

    float ar0 = 0.f, ag0 = 0.f, ab0 = 0.f;
    float ar1 = 0.f, ag1 = 0.f, ab1 = 0.f;

    float4 pa = prm4[0];
    float4 pb = prm4[1];
#pragma unroll 4
    for (int n = 0; n < 128; ++n) {
        float4 na = prm4[2 * n + 2];   // prefetch next (last iter reads pad/next chunk)
        float4 nb = prm4[2 * n + 3];

        float a = pa.x, b = pa.y, cc = pa.z, mx = pa.w;
        float my = pb.x, wr = pb.y, wg = pb.z, wb = pb.w;

        float dy   = y - my;
        float bdy  = b * dy;
        float cdy2 = cc * (dy * dy);

        float dx0 = x0 - mx, dx1 = x1 - mx;
        float q0 = fmaf(fmaf(a, dx0, bdy), dx0, cdy2);
        float q1 = fmaf(fmaf(a, dx1, bdy), dx1, cdy2);

        float e0 = __builtin_amdgcn_exp2f(q0);
        float e1 = __builtin_amdgcn_exp2f(q1);

        ar0 = fmaf(e0, wr, ar0); ag0 = fmaf(e0, wg, ag0); ab0 = fmaf(e0, wb, ab0);
        ar1 = fmaf(e1, wr, ar1); ag1 = fmaf(e1, wg, ag1); ab1 = fmaf(e1, wb, ab1);

        pa = na; pb = nb;
    }

    // combine the 4 gaussian-chunk partials (stride-7 pad: 2-way conflicts max)
    __shared__ float red[4][64][7];
    red[wv][lane][0] = ar0; red[wv][lane][1] = ag0; red[wv][lane][2] = ab0;
    red[wv][lane][3] = ar1; red[wv][lane][4] = ag1; red[wv][lane][5] = ab1;
    __syncthreads();

    if (wv == 0) {
        float v0 = red[0][lane][0] + red[1][lane][0] + red[2][lane][0] + red[3][lane][0];
        float v1 = red[0][lane][1] + red[1][lane][1] + red[2][lane][1] + red[3][lane][1];
        float v2 = red[0][lane][2] + red[1][lane][2] + red[2][lane][2] + red[3][lane][2];
        float v3 = red[0][lane][3] + red[1][lane][3] + red[2][lane][3] + red[3][lane][3];
        float v4 = red[0][lane][4] + red[1][lane][4] + red[2][lane][4] + red[3][lane][4];
        float v5 = red[0][lane][5] + red[1][lane][5] + red[2][lane][5] + red[3][lane][5];

        // reduce the 512 per-gaussian max slots: 8 per lane + shfl tree
        const float4* sl = reinterpret_cast<const float4*>(ws + SLOT_OFF) + 2 * lane;
        float4 s0 = sl[0], s1 = sl[1];
        float m = fmaxf(fmaxf(fmaxf(s0.x, s0.y), fmaxf(s0.z, s0.w)),
                        fmaxf(fmaxf(s1.x, s1.y), fmaxf(s1.z, s1.w)));
#pragma unroll
        for (int off = 32; off > 0; off >>= 1)
            m = fmaxf(m, __shfl_xor(m, off));
        float invmax = __builtin_amdgcn_exp2f(-m);   // 1 / max(prob)

        const float KE = 1.4426950408889634f;  // log2(e)
        v0 *= invmax; v1 *= invmax; v2 *= invmax;
        v3 *= invmax; v4 *= invmax; v5 *= invmax;
        v0 = __builtin_amdgcn_rcpf(1.0f + __builtin_amdgcn_exp2f(-KE * v0));
        v1 = __builtin_amdgcn_rcpf(1.0f + __builtin_amdgcn_exp2f(-KE * v1));
        v2 = __builtin_amdgcn_rcpf(1.0f + __builtin_amdgcn_exp2f(-KE * v2));
        v3 = __builtin_amdgcn_rcpf(1.0f + __builtin_amdgcn_exp2f(-KE * v3));
        v4 = __builtin_amdgcn_rcpf(1.0f + __builtin_amdgcn_exp2f(-KE * v4));
        v5 = __builtin_amdgcn_rcpf(1.0f + __builtin_amdgcn_exp2f(-KE * v5));

        float* o = out + (size_t)pbase * 3;  // 6 consecutive floats, 8B-aligned
        *reinterpret_cast<float2*>(o + 0) = make_float2(v0, v1);
        *reinterpret_cast<float2*>(o + 2) = make_float2(v2, v3);
        *reinterpret_cast<float2*>(o + 4) = make_float2(v4, v5);
    }
}

extern "C" void kernel_launch(void* const* d_in, const int* in_sizes, int n_in,
                              void* d_out, int out_size, void* d_ws, size_t ws_size,
                              hipStream_t stream) {
    const float* mean   = (const float*)d_in[0];
    const float* alpha  = (const float*)d_in[1];
    const float* scale  = (const float*)d_in[2];
    const float* theta  = (const float*)d_in[3];
    const float* rgb    = (const float*)d_in[4];
    const float* pixels = (const float*)d_in[5];
    float* out = (float*)d_out;
    float* ws  = (float*)d_ws;

    // 1 wave per gaussian
    prep_kernel<<<512, 64, 0, stream>>>(mean, alpha, scale, theta, rgb, pixels, ws);

    // 131072 pixel-pairs / 64 per block = 2048 blocks (8 blocks/CU)
    splat_kernel<<<2048, 256, 0, stream>>>(pixels, ws, out);
}

// Round 6
// 101.368 us; speedup vs baseline: 1.2932x; 1.2932x over previous
//
#include <hip/hip_runtime.h>

#define NG 512
#define PLANE 512

typedef float v2f __attribute__((ext_vector_type(2)));

// ws layout (float index):
//   [16 .. 16+8*513)   : packed params, 8 floats per gaussian:
//                        {A, B, C, mx, my, wr, wg, wb} (entry 512 = prefetch pad)
//   [4352 .. 4864)     : per-gaussian max slots t[n] = max log2(prob_n)
#define PRM_OFF  16
#define SLOT_OFF 4352

// One wave per gaussian: params computed redundantly in all lanes (HW trig),
// lane 0 publishes packed params; lanes scan 512 rows (8/lane) for the exact
// discrete max of t = log2(prob) (concave parabola in x per row -> vertex
// +/- lattice candidates), shfl-reduce, lane 0 stores the slot.
__global__ __launch_bounds__(64) void prep_kernel(
    const float* __restrict__ mean, const float* __restrict__ alpha,
    const float* __restrict__ scale, const float* __restrict__ theta,
    const float* __restrict__ rgb, const float* __restrict__ pixels,
    float* __restrict__ ws) {
    const int n    = blockIdx.x;        // 0..511
    const int lane = threadIdx.x;       // 0..63

    const float TWO_PI = 6.283185307179586f;
    float th = theta[n];
    float c = __builtin_amdgcn_cosf(th);   // cos(2*pi*th): v_cos takes revolutions
    float s = __builtin_amdgcn_sinf(th);
    float sx = scale[2 * n], sy = scale[2 * n + 1];

    // cov = rot @ smat @ smat^T @ rot^T (reference f32 order)
    float m200 = (c * sx) * sx;
    float m201 = (-(s * sy)) * sy;
    float m210 = (s * sx) * sx;
    float m211 = (c * sy) * sy;
    float a   = m200 * c + m201 * (-s);
    float b01 = m200 * s + m201 * c;
    float b10 = m210 * c + m211 * (-s);
    float d   = m210 * s + m211 * c;

    float det = a * d - b01 * b10;
    float rdet = __builtin_amdgcn_rcpf(det);
    float inv00 = d * rdet;
    float inv01 = -b01 * rdet;
    float inv10 = -b10 * rdet;
    float inv11 = a * rdet;

    float norm = __builtin_amdgcn_rcpf(TWO_PI * __builtin_amdgcn_sqrtf(det));
    const float K = -0.5f * 1.4426950408889634f;  // -0.5 * log2(e)

    float A_ = K * inv00;
    float B_ = K * (inv01 + inv10);
    float C_ = K * inv11;
    float mx = mean[2 * n], my = mean[2 * n + 1];
    // Lg = log2(norm) = -log2(2*pi) - 0.5*log2(det)
    float Lg = fmaf(-0.5f, __builtin_amdgcn_logf(det), -2.651496129472319f);

    if (lane == 0) {
        float w = alpha[n] * norm;
        float4* p = (float4*)(ws + PRM_OFF + 8 * n);
        p[0] = make_float4(A_, B_, C_, mx);
        p[1] = make_float4(my, w * rgb[3 * n], w * rgb[3 * n + 1], w * rgb[3 * n + 2]);
    }

    // row scan: 8 rows per lane
    float inv2A = __builtin_amdgcn_rcpf(2.0f * A_);
    float t = -1e30f;
#pragma unroll
    for (int k = 0; k < 8; ++k) {
        int r = lane + (k << 6);
        float y  = pixels[(r << 10) + 1];
        float dy = y - my;
        float bdy  = B_ * dy;
        float cdy2 = C_ * (dy * dy);
        float xstar = mx - bdy * inv2A;
        float xs = fminf(fmaxf(xstar, 0.0f), 1.0f);   // NaN-safe clamp
        int i1 = min((int)(xs * 511.0f), 510);
#pragma unroll
        for (int kk = -1; kk <= 2; ++kk) {
            int i = max(0, min(i1 + kk, 511));
            float x = pixels[(r << 10) + (i << 1)];
            float dx = x - mx;
            float q = fmaf(fmaf(A_, dx, bdy), dx, cdy2);
            t = fmaxf(t, q);
        }
    }
    t += Lg;
#pragma unroll
    for (int off = 32; off > 0; off >>= 1)
        t = fmaxf(t, __shfl_xor(t, off));
    if (lane == 0) ws[SLOT_OFF + n] = t;
}

// 2048 blocks x 256 threads (8 blocks/CU -> 32 waves/CU). Block covers 64
// pixel-pairs; wave wv handles gaussians [wv*128,(wv+1)*128). wv is forced
// into an SGPR via readfirstlane so param loads stay on the s_load path.
// Packed float2 math (v_pk_fma_f32) for the 2 pixels. Partials combine in
// LDS; wave 0 does max-normalize + sigmoid + store.
__global__ __launch_bounds__(256, 8) void splat_kernel(
    const float* __restrict__ pixels, const float* __restrict__ ws,
    float* __restrict__ out) {
    const int tid  = threadIdx.x;
    const int wv   = __builtin_amdgcn_readfirstlane(tid >> 6);  // scalar chunk id
    const int lane = tid & 63;
    const int pair = blockIdx.x * 64 + lane;     // 0..131071
    const int row  = pair >> 8;
    const int col0 = (pair & 255) << 1;
    const int pbase = row * PLANE + col0;

    // one dwordx4: {x0, y, x1, y}
    float4 pix = *reinterpret_cast<const float4*>(pixels + 2 * pbase);
    const float y = pix.y;
    const v2f xx = {pix.x, pix.z};

    const float4* prm4 = reinterpret_cast<const float4*>(ws + PRM_OFF) + (wv << 8);

    v2f accr = {0.f, 0.f}, accg = {0.f, 0.f}, accb = {0.f, 0.f};

    float4 pa = prm4[0];
    float4 pb = prm4[1];
#pragma unroll 4
    for (int n = 0; n < 128; ++n) {
        float4 na = prm4[2 * n + 2];   // prefetch next (last iter reads scratch pad)
        float4 nb = prm4[2 * n + 3];

        float a = pa.x, b = pa.y, cc = pa.z, mx = pa.w;
        float my = pb.x, wr = pb.y, wg = pb.z, wb = pb.w;

        float dy   = y - my;
        float bdy  = b * dy;
        float cdy2 = cc * (dy * dy);

        v2f dx = xx - (v2f){mx, mx};
        v2f t  = __builtin_elementwise_fma(dx, (v2f){a, a}, (v2f){bdy, bdy});
        v2f q  = __builtin_elementwise_fma(t, dx, (v2f){cdy2, cdy2});

        v2f e = {__builtin_amdgcn_exp2f(q.x), __builtin_amdgcn_exp2f(q.y)};

        accr = __builtin_elementwise_fma(e, (v2f){wr, wr}, accr);
        accg = __builtin_elementwise_fma(e, (v2f){wg, wg}, accg);
        accb = __builtin_elementwise_fma(e, (v2f){wb, wb}, accb);

        pa = na; pb = nb;
    }

    // combine the 4 gaussian-chunk partials
    __shared__ float red[4][64][7];
    red[wv][lane][0] = accr.x; red[wv][lane][1] = accg.x; red[wv][lane][2] = accb.x;
    red[wv][lane][3] = accr.y; red[wv][lane][4] = accg.y; red[wv][lane][5] = accb.y;
    __syncthreads();

    if (wv == 0) {
        float v0 = red[0][lane][0] + red[1][lane][0] + red[2][lane][0] + red[3][lane][0];
        float v1 = red[0][lane][1] + red[1][lane][1] + red[2][lane][1] + red[3][lane][1];
        float v2 = red[0][lane][2] + red[1][lane][2] + red[2][lane][2] + red[3][lane][2];
        float v3 = red[0][lane][3] + red[1][lane][3] + red[2][lane][3] + red[3][lane][3];
        float v4 = red[0][lane][4] + red[1][lane][4] + red[2][lane][4] + red[3][lane][4];
        float v5 = red[0][lane][5] + red[1][lane][5] + red[2][lane][5] + red[3][lane][5];

        // reduce the 512 per-gaussian max slots: 8 per lane + shfl tree
        const float4* sl = reinterpret_cast<const float4*>(ws + SLOT_OFF) + 2 * lane;
        float4 s0 = sl[0], s1 = sl[1];
        float m = fmaxf(fmaxf(fmaxf(s0.x, s0.y), fmaxf(s0.z, s0.w)),
                        fmaxf(fmaxf(s1.x, s1.y), fmaxf(s1.z, s1.w)));
#pragma unroll
        for (int off = 32; off > 0; off >>= 1)
            m = fmaxf(m, __shfl_xor(m, off));
        float invmax = __builtin_amdgcn_exp2f(-m);   // 1 / max(prob)

        const float KE = 1.4426950408889634f;  // log2(e)
        v0 *= invmax; v1 *= invmax; v2 *= invmax;
        v3 *= invmax; v4 *= invmax; v5 *= invmax;
        v0 = __builtin_amdgcn_rcpf(1.0f + __builtin_amdgcn_exp2f(-KE * v0));
        v1 = __builtin_amdgcn_rcpf(1.0f + __builtin_amdgcn_exp2f(-KE * v1));
        v2 = __builtin_amdgcn_rcpf(1.0f + __builtin_amdgcn_exp2f(-KE * v2));
        v3 = __builtin_amdgcn_rcpf(1.0f + __builtin_amdgcn_exp2f(-KE * v3));
        v4 = __builtin_amdgcn_rcpf(1.0f + __builtin_amdgcn_exp2f(-KE * v4));
        v5 = __builtin_amdgcn_rcpf(1.0f + __builtin_amdgcn_exp2f(-KE * v5));

        float* o = out + (size_t)pbase * 3;  // 6 consecutive floats, 8B-aligned
        *reinterpret_cast<float2*>(o + 0) = make_float2(v0, v1);
        *reinterpret_cast<float2*>(o + 2) = make_float2(v2, v3);
        *reinterpret_cast<float2*>(o + 4) = make_float2(v4, v5);
    }
}

extern "C" void kernel_launch(void* const* d_in, const int* in_sizes, int n_in,
                              void* d_out, int out_size, void* d_ws, size_t ws_size,
                              hipStream_t stream) {
    const float* mean   = (const float*)d_in[0];
    const float* alpha  = (const float*)d_in[1];
    const float* scale  = (const float*)d_in[2];
    const float* theta  = (const float*)d_in[3];
    const float* rgb    = (const float*)d_in[4];
    const float* pixels = (const float*)d_in[5];
    float* out = (float*)d_out;
    float* ws  = (float*)d_ws;

    // 1 wave per gaussian
    prep_kernel<<<512, 64, 0, stream>>>(mean, alpha, scale, theta, rgb, pixels, ws);

    // 131072 pixel-pairs / 64 per block = 2048 blocks (8 blocks/CU)
    splat_kernel<<<2048, 256, 0, stream>>>(pixels, ws, out);
}